// Round 1
// baseline (5456.565 us; speedup 1.0000x reference)
//
#include <hip/hip_runtime.h>

#define B_  2
#define S_  2048
#define D_  1024
#define H_  16
#define DH_ 64
#define NDH (H_*DH_)   // 1024

// out = A(M,K) @ W(K,N) + bias
// mode 0: out[m*N+n]
// mode 1: split-head write  out[((b*H+h)*S+s)*DH + d]  (Q/K/V [B,H,S,DH] layout)
__global__ void gemm16(const float* __restrict__ A, const float* __restrict__ W,
                       const float* __restrict__ bias, float* __restrict__ out,
                       int M, int N, int K, int mode) {
    __shared__ float As[16][17];
    __shared__ float Ws[16][17];
    int tx = threadIdx.x, ty = threadIdx.y;
    int m = blockIdx.y * 16 + ty;
    int n = blockIdx.x * 16 + tx;
    float acc = 0.f;
    for (int k0 = 0; k0 < K; k0 += 16) {
        As[ty][tx] = A[(size_t)m * K + k0 + tx];
        Ws[ty][tx] = W[(size_t)(k0 + ty) * N + n];
        __syncthreads();
#pragma unroll
        for (int kk = 0; kk < 16; ++kk) acc += As[ty][kk] * Ws[kk][tx];
        __syncthreads();
    }
    acc += bias[n];
    if (mode == 0) {
        out[(size_t)m * N + n] = acc;
    } else {
        int b = m / S_, s = m % S_;
        int h = n / DH_, d = n % DH_;
        out[(((size_t)b * H_ + h) * S_ + s) * DH_ + d] = acc;
    }
}

// One block (256 thr) per (q, h, b). Q/K/V in [B,H,S,DH]; O in [B,S,H*DH].
__global__ void attn(const float* __restrict__ Q, const float* __restrict__ K,
                     const float* __restrict__ V, float* __restrict__ O) {
    int q = blockIdx.x, h = blockIdx.y, b = blockIdx.z;
    const float* Qp = Q + (((size_t)b * H_ + h) * S_ + q) * DH_;
    const float* Kp = K + (((size_t)b * H_ + h) * S_) * DH_;
    const float* Vp = V + (((size_t)b * H_ + h) * S_) * DH_;

    __shared__ float qv[DH_];
    __shared__ float sc[S_];      // 8 KB score buffer
    __shared__ float red[256];
    __shared__ float op[4][DH_];

    int tid = threadIdx.x;
    if (tid < DH_) qv[tid] = Qp[tid];
    __syncthreads();

    const int nk = q + 1;               // causal: keys 0..q
    const float scale = 0.125f;         // 1/sqrt(64)

    float lmax = -1e30f;
    for (int j = tid; j < nk; j += 256) {
        const float* kp = Kp + (size_t)j * DH_;
        float s = 0.f;
#pragma unroll
        for (int d = 0; d < DH_; ++d) s += qv[d] * kp[d];
        s *= scale;
        sc[j] = s;
        lmax = fmaxf(lmax, s);
    }
    red[tid] = lmax;
    __syncthreads();
    for (int s2 = 128; s2 > 0; s2 >>= 1) {
        if (tid < s2) red[tid] = fmaxf(red[tid], red[tid + s2]);
        __syncthreads();
    }
    float mx = red[0];
    __syncthreads();

    float lsum = 0.f;
    for (int j = tid; j < nk; j += 256) {
        float e = expf(sc[j] - mx);
        sc[j] = e;
        lsum += e;
    }
    red[tid] = lsum;
    __syncthreads();
    for (int s2 = 128; s2 > 0; s2 >>= 1) {
        if (tid < s2) red[tid] += red[tid + s2];
        __syncthreads();
    }
    float inv = 1.0f / red[0];

    // thread t = c*64+d : partial over keys j ≡ c (mod 4); V reads coalesced
    int d = tid & 63, c = tid >> 6;
    float part = 0.f;
    for (int j = c; j < nk; j += 4) part += sc[j] * Vp[(size_t)j * DH_ + d];
    op[c][d] = part;
    __syncthreads();
    if (tid < DH_) {
        float o = (op[0][tid] + op[1][tid] + op[2][tid] + op[3][tid]) * inv;
        O[((size_t)b * S_ + q) * NDH + h * DH_ + tid] = o;
    }
}

extern "C" void kernel_launch(void* const* d_in, const int* in_sizes, int n_in,
                              void* d_out, int out_size, void* d_ws, size_t ws_size,
                              hipStream_t stream) {
    const float* x  = (const float*)d_in[0];
    const float* Wq = (const float*)d_in[1];
    const float* bq = (const float*)d_in[2];
    const float* Wk = (const float*)d_in[3];
    const float* bk = (const float*)d_in[4];
    const float* Wv = (const float*)d_in[5];
    const float* bv = (const float*)d_in[6];
    const float* Wo = (const float*)d_in[7];
    const float* bo = (const float*)d_in[8];
    float* out = (float*)d_out;

    float* ws = (float*)d_ws;
    const size_t per = (size_t)B_ * H_ * S_ * DH_;   // 4M floats = 16 MB
    float* Q = ws;
    float* K = ws + per;
    float* V = ws + 2 * per;
    float* O = ws + 3 * per;

    dim3 blk(16, 16);
    dim3 grd(NDH / 16, (B_ * S_) / 16);
    gemm16<<<grd, blk, 0, stream>>>(x, Wq, bq, Q, B_ * S_, NDH, D_, 1);
    gemm16<<<grd, blk, 0, stream>>>(x, Wk, bk, K, B_ * S_, NDH, D_, 1);
    gemm16<<<grd, blk, 0, stream>>>(x, Wv, bv, V, B_ * S_, NDH, D_, 1);

    attn<<<dim3(S_, H_, B_), 256, 0, stream>>>(Q, K, V, O);

    gemm16<<<dim3(D_ / 16, (B_ * S_) / 16), blk, 0, stream>>>(O, Wo, bo, out,
                                                              B_ * S_, D_, NDH, 0);
}

// Round 2
// 424.049 us; speedup vs baseline: 12.8678x; 12.8678x over previous
//
#include <hip/hip_runtime.h>

#define B_  2
#define S_  2048
#define D_  1024
#define H_  16
#define DH_ 64
#define NDH (H_*DH_)   // 1024
#define BS_ (B_*S_)    // 4096

typedef __bf16 bf16;
typedef bf16 bf16x8 __attribute__((ext_vector_type(8)));
typedef bf16 bf16x4 __attribute__((ext_vector_type(4)));
typedef float f32x4 __attribute__((ext_vector_type(4)));

// ---------------- cast fp32 -> bf16 ----------------
__global__ void cast_bf16(const float* __restrict__ in, bf16* __restrict__ out, int n) {
    int i = (blockIdx.x * blockDim.x + threadIdx.x) * 4;
    if (i < n) {
        float4 v = *(const float4*)(in + i);
        bf16x4 o = { (bf16)v.x, (bf16)v.y, (bf16)v.z, (bf16)v.w };
        *(bf16x4*)(out + i) = o;
    }
}

// ---------------- transpose-cast W[K][N] fp32 -> Wt[N][K] bf16 ----------------
__global__ void transW(const float* __restrict__ W, bf16* __restrict__ Wt, int K, int N) {
    __shared__ float T[32][33];
    int k0 = blockIdx.y * 32, n0 = blockIdx.x * 32;
    int t = threadIdx.x;
    int r = t >> 3, c = (t & 7) * 4;
    float4 v = *(const float4*)(W + (size_t)(k0 + r) * N + n0 + c);
    T[c + 0][r] = v.x; T[c + 1][r] = v.y; T[c + 2][r] = v.z; T[c + 3][r] = v.w;
    __syncthreads();
    bf16x4 o = { (bf16)T[r][c], (bf16)T[r][c + 1], (bf16)T[r][c + 2], (bf16)T[r][c + 3] };
    *(bf16x4*)(Wt + (size_t)(n0 + r) * K + k0 + c) = o;
}

// ---------------- GEMM: C[M][N] = A[M][K] @ Bt[N][K]^T + bias ----------------
// mode 0: fp32 out[M][N];  mode 1: bf16 split-head out[B][H][S][DH]
#define GBM 64
#define GBN 64
#define GBK 32
__global__ __launch_bounds__(256) void gemm_bt(
        const bf16* __restrict__ A, const bf16* __restrict__ Bt,
        const float* __restrict__ bias, void* __restrict__ outp,
        int M, int N, int K, int mode) {
    __shared__ __align__(16) bf16 As[GBM][GBK + 8];
    __shared__ __align__(16) bf16 Bs[GBN][GBK + 8];
    int tid = threadIdx.x;
    int wave = tid >> 6, lane = tid & 63;
    int quad = lane >> 4, l16 = lane & 15;
    int bm = blockIdx.y * GBM, bn = blockIdx.x * GBN;
    int wm = (wave >> 1) * 32, wn = (wave & 1) * 32;

    int ls = tid >> 2;          // 0..63
    int lc = (tid & 3) * 8;     // 0,8,16,24
    const bf16* Ap = A + (size_t)(bm + ls) * K + lc;
    const bf16* Bp = Bt + (size_t)(bn + ls) * K + lc;

    f32x4 acc[2][2] = {};

    for (int k0 = 0; k0 < K; k0 += GBK) {
        bf16x8 av = *(const bf16x8*)(Ap + k0);
        bf16x8 bv = *(const bf16x8*)(Bp + k0);
        __syncthreads();
        *(bf16x8*)&As[ls][lc] = av;
        *(bf16x8*)&Bs[ls][lc] = bv;
        __syncthreads();
        bf16x8 a0 = *(const bf16x8*)&As[wm + l16][quad * 8];
        bf16x8 a1 = *(const bf16x8*)&As[wm + 16 + l16][quad * 8];
        bf16x8 b0 = *(const bf16x8*)&Bs[wn + l16][quad * 8];
        bf16x8 b1 = *(const bf16x8*)&Bs[wn + 16 + l16][quad * 8];
        acc[0][0] = __builtin_amdgcn_mfma_f32_16x16x32_bf16(a0, b0, acc[0][0], 0, 0, 0);
        acc[0][1] = __builtin_amdgcn_mfma_f32_16x16x32_bf16(a0, b1, acc[0][1], 0, 0, 0);
        acc[1][0] = __builtin_amdgcn_mfma_f32_16x16x32_bf16(a1, b0, acc[1][0], 0, 0, 0);
        acc[1][1] = __builtin_amdgcn_mfma_f32_16x16x32_bf16(a1, b1, acc[1][1], 0, 0, 0);
    }

    #pragma unroll
    for (int i = 0; i < 2; ++i)
      #pragma unroll
      for (int j = 0; j < 2; ++j)
        #pragma unroll
        for (int r = 0; r < 4; ++r) {
            int row = bm + wm + i * 16 + quad * 4 + r;
            int col = bn + wn + j * 16 + l16;
            float v = acc[i][j][r] + bias[col];
            if (mode == 0) {
                ((float*)outp)[(size_t)row * N + col] = v;
            } else {
                int bb = row >> 11, s = row & 2047;
                int hh = col >> 6, d = col & 63;
                ((bf16*)outp)[(((size_t)bb * H_ + hh) * S_ + s) * DH_ + d] = (bf16)v;
            }
        }
}

// ---------------- V[bh][s][d] -> Vt[bh][d][s] ----------------
__global__ void transV(const bf16* __restrict__ V, bf16* __restrict__ Vt) {
    __shared__ __align__(16) bf16 T[64][72];
    int s0 = blockIdx.x * 64;
    int bh = blockIdx.y;
    const bf16* Vp = V + ((size_t)bh * S_ + s0) * DH_;
    bf16* Vtp = Vt + (size_t)bh * DH_ * S_;
    int t = threadIdx.x;
    #pragma unroll
    for (int p = 0; p < 2; ++p) {
        int r = (t >> 3) + p * 32;   // s-local
        int c = (t & 7) * 8;         // d
        bf16x8 v = *(const bf16x8*)(Vp + (size_t)r * DH_ + c);
        #pragma unroll
        for (int j = 0; j < 8; ++j) T[c + j][r] = v[j];
    }
    __syncthreads();
    #pragma unroll
    for (int p = 0; p < 2; ++p) {
        int d = (t >> 3) + p * 32;
        int c = (t & 7) * 8;         // s-local
        bf16x8 v;
        #pragma unroll
        for (int j = 0; j < 8; ++j) v[j] = T[d][c + j];
        *(bf16x8*)(Vtp + (size_t)d * S_ + s0 + c) = v;
    }
}

// ---------------- flash attention ----------------
// grid (S/64, H, B), 256 thr. Q,K [bh][s][d] bf16; Vt [bh][d][s] bf16; O [b*s][NDH] bf16
__global__ __launch_bounds__(256) void flash_attn(
        const bf16* __restrict__ Q, const bf16* __restrict__ K,
        const bf16* __restrict__ Vt, bf16* __restrict__ O) {
    int qt = blockIdx.x;
    int h = blockIdx.y, b = blockIdx.z;
    int bh = b * H_ + h;
    int tid = threadIdx.x;
    int wave = tid >> 6, lane = tid & 63;
    int quad = lane >> 4, l16 = lane & 15;

    __shared__ __align__(16) bf16 P[4][16][72];

    int q0 = qt * 64 + wave * 16;
    const bf16* Qp = Q + ((size_t)bh * S_ + q0 + l16) * DH_ + quad * 8;
    bf16x8 qf0 = *(const bf16x8*)(Qp);
    bf16x8 qf1 = *(const bf16x8*)(Qp + 32);

    f32x4 oacc[4] = {};
    float m_run[4] = { -1e30f, -1e30f, -1e30f, -1e30f };
    float l_run[4] = {};

    const bf16* Kbase = K + (size_t)bh * S_ * DH_;
    const bf16* Vbase = Vt + (size_t)bh * DH_ * S_;

    for (int kt = 0; kt <= qt; ++kt) {
        int kv0 = kt * 64;
        f32x4 sacc[4] = {};
        #pragma unroll
        for (int ns = 0; ns < 4; ++ns) {
            const bf16* Kp = Kbase + (size_t)(kv0 + ns * 16 + l16) * DH_ + quad * 8;
            bf16x8 kf0 = *(const bf16x8*)(Kp);
            bf16x8 kf1 = *(const bf16x8*)(Kp + 32);
            sacc[ns] = __builtin_amdgcn_mfma_f32_16x16x32_bf16(qf0, kf0, sacc[ns], 0, 0, 0);
            sacc[ns] = __builtin_amdgcn_mfma_f32_16x16x32_bf16(qf1, kf1, sacc[ns], 0, 0, 0);
        }
        bool diag = (kt == qt);
        #pragma unroll
        for (int ns = 0; ns < 4; ++ns)
          #pragma unroll
          for (int r = 0; r < 4; ++r) {
            float s = sacc[ns][r] * 0.125f;
            if (diag) {
                int kv = kv0 + ns * 16 + l16;
                int q = q0 + quad * 4 + r;
                if (kv > q) s = -1e30f;
            }
            sacc[ns][r] = s;
          }
        float alpha[4];
        #pragma unroll
        for (int r = 0; r < 4; ++r) {
            float mx = fmaxf(fmaxf(sacc[0][r], sacc[1][r]), fmaxf(sacc[2][r], sacc[3][r]));
            mx = fmaxf(mx, __shfl_xor(mx, 1));
            mx = fmaxf(mx, __shfl_xor(mx, 2));
            mx = fmaxf(mx, __shfl_xor(mx, 4));
            mx = fmaxf(mx, __shfl_xor(mx, 8));
            float mnew = fmaxf(m_run[r], mx);
            alpha[r] = __expf(m_run[r] - mnew);
            m_run[r] = mnew;
            float psum = 0.f;
            #pragma unroll
            for (int ns = 0; ns < 4; ++ns) {
                float p = __expf(sacc[ns][r] - mnew);
                sacc[ns][r] = p;
                psum += p;
            }
            psum += __shfl_xor(psum, 1);
            psum += __shfl_xor(psum, 2);
            psum += __shfl_xor(psum, 4);
            psum += __shfl_xor(psum, 8);
            l_run[r] = l_run[r] * alpha[r] + psum;
        }
        #pragma unroll
        for (int ns = 0; ns < 4; ++ns)
          #pragma unroll
          for (int r = 0; r < 4; ++r)
            P[wave][quad * 4 + r][ns * 16 + l16] = (bf16)sacc[ns][r];
        #pragma unroll
        for (int ds = 0; ds < 4; ++ds)
          #pragma unroll
          for (int r = 0; r < 4; ++r)
            oacc[ds][r] *= alpha[r];
        #pragma unroll
        for (int ks = 0; ks < 2; ++ks) {
            bf16x8 pf = *(const bf16x8*)&P[wave][l16][ks * 32 + quad * 8];
            #pragma unroll
            for (int ds = 0; ds < 4; ++ds) {
                const bf16* Vp = Vbase + (size_t)(ds * 16 + l16) * S_ + kv0 + ks * 32 + quad * 8;
                bf16x8 vf = *(const bf16x8*)(Vp);
                oacc[ds] = __builtin_amdgcn_mfma_f32_16x16x32_bf16(pf, vf, oacc[ds], 0, 0, 0);
            }
        }
    }
    #pragma unroll
    for (int r = 0; r < 4; ++r) {
        float inv = 1.0f / l_run[r];
        int q = q0 + quad * 4 + r;
        bf16* Op = O + ((size_t)b * S_ + q) * NDH + h * DH_;
        #pragma unroll
        for (int ds = 0; ds < 4; ++ds)
            Op[ds * 16 + l16] = (bf16)(oacc[ds][r] * inv);
    }
}

extern "C" void kernel_launch(void* const* d_in, const int* in_sizes, int n_in,
                              void* d_out, int out_size, void* d_ws, size_t ws_size,
                              hipStream_t stream) {
    const float* x  = (const float*)d_in[0];
    const float* Wq = (const float*)d_in[1];
    const float* bq = (const float*)d_in[2];
    const float* Wk = (const float*)d_in[3];
    const float* bk = (const float*)d_in[4];
    const float* Wv = (const float*)d_in[5];
    const float* bv = (const float*)d_in[6];
    const float* Wo = (const float*)d_in[7];
    const float* bo = (const float*)d_in[8];
    float* out = (float*)d_out;

    bf16* ws = (bf16*)d_ws;
    const size_t M1 = (size_t)1024 * 1024;
    bf16* xb  = ws;                    // 4M
    bf16* WqT = ws + 4 * M1;           // 1M each
    bf16* WkT = ws + 5 * M1;
    bf16* WvT = ws + 6 * M1;
    bf16* WoT = ws + 7 * M1;
    bf16* Qw  = ws + 8 * M1;           // 4M each
    bf16* Kw  = ws + 12 * M1;
    bf16* Vw  = ws + 16 * M1;
    bf16* Vtw = ws + 20 * M1;
    bf16* Ow  = ws + 24 * M1;

    int nx = BS_ * D_;
    cast_bf16<<<nx / 4 / 256, 256, 0, stream>>>(x, xb, nx);
    dim3 tw(32, 32);
    transW<<<tw, 256, 0, stream>>>(Wq, WqT, D_, NDH);
    transW<<<tw, 256, 0, stream>>>(Wk, WkT, D_, NDH);
    transW<<<tw, 256, 0, stream>>>(Wv, WvT, D_, NDH);
    transW<<<tw, 256, 0, stream>>>(Wo, WoT, NDH, D_);

    dim3 gg(NDH / GBN, BS_ / GBM);
    gemm_bt<<<gg, 256, 0, stream>>>(xb, WqT, bq, Qw, BS_, NDH, D_, 1);
    gemm_bt<<<gg, 256, 0, stream>>>(xb, WkT, bk, Kw, BS_, NDH, D_, 1);
    gemm_bt<<<gg, 256, 0, stream>>>(xb, WvT, bv, Vw, BS_, NDH, D_, 1);

    transV<<<dim3(S_ / 64, B_ * H_), 256, 0, stream>>>(Vw, Vtw);

    flash_attn<<<dim3(S_ / 64, H_, B_), 256, 0, stream>>>(Qw, Kw, Vtw, Ow);

    gemm_bt<<<dim3(D_ / GBN, BS_ / GBM), 256, 0, stream>>>(Ow, WoT, bo, out, BS_, D_, NDH, 0);
}

// Round 3
// 268.521 us; speedup vs baseline: 20.3208x; 1.5792x over previous
//
#include <hip/hip_runtime.h>

#define B_  2
#define S_  2048
#define D_  1024
#define H_  16
#define DH_ 64
#define NDH (H_*DH_)   // 1024
#define BS_ (B_*S_)    // 4096

typedef __bf16 bf16;
typedef bf16 bf16x8 __attribute__((ext_vector_type(8)));
typedef bf16 bf16x4 __attribute__((ext_vector_type(4)));
typedef float f32x4 __attribute__((ext_vector_type(4)));

#define AS1 __attribute__((address_space(1)))
#define AS3 __attribute__((address_space(3)))
__device__ inline void gld16(const bf16* g, bf16* l) {
    __builtin_amdgcn_global_load_lds((const AS1 void*)g, (AS3 void*)l, 16, 0, 0);
}

// ---------------- cast fp32 -> bf16 ----------------
__global__ void cast_bf16(const float* __restrict__ in, bf16* __restrict__ out, int n) {
    int i = (blockIdx.x * blockDim.x + threadIdx.x) * 4;
    if (i < n) {
        float4 v = *(const float4*)(in + i);
        bf16x4 o = { (bf16)v.x, (bf16)v.y, (bf16)v.z, (bf16)v.w };
        *(bf16x4*)(out + i) = o;
    }
}

// ---------------- transpose-cast W[K][N] fp32 -> Wt[N][K] bf16 ----------------
__global__ void transW(const float* __restrict__ W, bf16* __restrict__ Wt, int K, int N) {
    __shared__ float T[32][33];
    int k0 = blockIdx.y * 32, n0 = blockIdx.x * 32;
    int t = threadIdx.x;
    int r = t >> 3, c = (t & 7) * 4;
    float4 v = *(const float4*)(W + (size_t)(k0 + r) * N + n0 + c);
    T[c + 0][r] = v.x; T[c + 1][r] = v.y; T[c + 2][r] = v.z; T[c + 3][r] = v.w;
    __syncthreads();
    bf16x4 o = { (bf16)T[r][c], (bf16)T[r][c + 1], (bf16)T[r][c + 2], (bf16)T[r][c + 3] };
    *(bf16x4*)(Wt + (size_t)(n0 + r) * K + k0 + c) = o;
}

// ---------------- fused QKV GEMM: 128x128 tile, global_load_lds ----------------
// A [4096][1024] bf16, Bt [3072][1024] bf16 (rows: Wq|Wk|Wv transposed)
// out: split-head bf16, Q at Qout, K at Qout+PER, V at Qout+2*PER, layout [B][H][S][DH]
#define PER ((size_t)B_*H_*S_*DH_)   // 4M elements
__global__ __launch_bounds__(256) void qkv_gemm(
        const bf16* __restrict__ A, const bf16* __restrict__ Bt,
        const float* __restrict__ bq, const float* __restrict__ bk,
        const float* __restrict__ bv, bf16* __restrict__ Qout) {
    __shared__ __align__(16) bf16 As[128 * 32];
    __shared__ __align__(16) bf16 Bs[128 * 32];
    int tid = threadIdx.x, wave = tid >> 6, lane = tid & 63;
    int quad = lane >> 4, l16 = lane & 15;
    int bm = blockIdx.y * 128, bn = blockIdx.x * 128;
    int wm = (wave >> 1) * 64, wn = (wave & 1) * 64;

    int sr = lane >> 2, sc = (lane & 3) * 8;
    const bf16* Ag0 = A + (size_t)(bm + (wave * 2 + 0) * 16 + sr) * 1024 + sc;
    const bf16* Ag1 = A + (size_t)(bm + (wave * 2 + 1) * 16 + sr) * 1024 + sc;
    const bf16* Bg0 = Bt + (size_t)(bn + (wave * 2 + 0) * 16 + sr) * 1024 + sc;
    const bf16* Bg1 = Bt + (size_t)(bn + (wave * 2 + 1) * 16 + sr) * 1024 + sc;
    bf16* Al0 = &As[(wave * 2 + 0) * 512];
    bf16* Al1 = &As[(wave * 2 + 1) * 512];
    bf16* Bl0 = &Bs[(wave * 2 + 0) * 512];
    bf16* Bl1 = &Bs[(wave * 2 + 1) * 512];

    f32x4 acc[4][4] = {};

    for (int k0 = 0; k0 < 1024; k0 += 32) {
        gld16(Ag0 + k0, Al0);
        gld16(Ag1 + k0, Al1);
        gld16(Bg0 + k0, Bl0);
        gld16(Bg1 + k0, Bl1);
        __syncthreads();
        bf16x8 af[4], bfr[4];
        #pragma unroll
        for (int i = 0; i < 4; ++i)
            af[i] = *(const bf16x8*)&As[(wm + i * 16 + l16) * 32 + quad * 8];
        #pragma unroll
        for (int j = 0; j < 4; ++j)
            bfr[j] = *(const bf16x8*)&Bs[(wn + j * 16 + l16) * 32 + quad * 8];
        #pragma unroll
        for (int i = 0; i < 4; ++i)
          #pragma unroll
          for (int j = 0; j < 4; ++j)
            acc[i][j] = __builtin_amdgcn_mfma_f32_16x16x32_bf16(af[i], bfr[j], acc[i][j], 0, 0, 0);
        __syncthreads();
    }

    #pragma unroll
    for (int i = 0; i < 4; ++i)
      #pragma unroll
      for (int j = 0; j < 4; ++j) {
        int col = bn + wn + j * 16 + l16;
        float bias = (col < 1024) ? bq[col] : (col < 2048) ? bk[col - 1024] : bv[col - 2048];
        int qkv = col >> 10, cw = col & 1023;
        int hh = cw >> 6, d = cw & 63;
        #pragma unroll
        for (int r = 0; r < 4; ++r) {
            int row = bm + wm + i * 16 + quad * 4 + r;
            int bb = row >> 11, s = row & 2047;
            Qout[(size_t)qkv * PER + (((size_t)bb * H_ + hh) * S_ + s) * DH_ + d] =
                (bf16)(acc[i][j][r] + bias);
        }
      }
}

// ---------------- GEMM (64x64): C[M][N] = A[M][K] @ Bt[N][K]^T + bias, fp32 out ----------------
#define GBM 64
#define GBN 64
#define GBK 32
__global__ __launch_bounds__(256) void gemm_bt(
        const bf16* __restrict__ A, const bf16* __restrict__ Bt,
        const float* __restrict__ bias, float* __restrict__ out,
        int M, int N, int K) {
    __shared__ __align__(16) bf16 As[GBM][GBK + 8];
    __shared__ __align__(16) bf16 Bs[GBN][GBK + 8];
    int tid = threadIdx.x;
    int wave = tid >> 6, lane = tid & 63;
    int quad = lane >> 4, l16 = lane & 15;
    int bm = blockIdx.y * GBM, bn = blockIdx.x * GBN;
    int wm = (wave >> 1) * 32, wn = (wave & 1) * 32;

    int ls = tid >> 2;
    int lc = (tid & 3) * 8;
    const bf16* Ap = A + (size_t)(bm + ls) * K + lc;
    const bf16* Bp = Bt + (size_t)(bn + ls) * K + lc;

    f32x4 acc[2][2] = {};

    for (int k0 = 0; k0 < K; k0 += GBK) {
        bf16x8 av = *(const bf16x8*)(Ap + k0);
        bf16x8 bv = *(const bf16x8*)(Bp + k0);
        __syncthreads();
        *(bf16x8*)&As[ls][lc] = av;
        *(bf16x8*)&Bs[ls][lc] = bv;
        __syncthreads();
        bf16x8 a0 = *(const bf16x8*)&As[wm + l16][quad * 8];
        bf16x8 a1 = *(const bf16x8*)&As[wm + 16 + l16][quad * 8];
        bf16x8 b0 = *(const bf16x8*)&Bs[wn + l16][quad * 8];
        bf16x8 b1 = *(const bf16x8*)&Bs[wn + 16 + l16][quad * 8];
        acc[0][0] = __builtin_amdgcn_mfma_f32_16x16x32_bf16(a0, b0, acc[0][0], 0, 0, 0);
        acc[0][1] = __builtin_amdgcn_mfma_f32_16x16x32_bf16(a0, b1, acc[0][1], 0, 0, 0);
        acc[1][0] = __builtin_amdgcn_mfma_f32_16x16x32_bf16(a1, b0, acc[1][0], 0, 0, 0);
        acc[1][1] = __builtin_amdgcn_mfma_f32_16x16x32_bf16(a1, b1, acc[1][1], 0, 0, 0);
    }

    #pragma unroll
    for (int i = 0; i < 2; ++i)
      #pragma unroll
      for (int j = 0; j < 2; ++j)
        #pragma unroll
        for (int r = 0; r < 4; ++r) {
            int row = bm + wm + i * 16 + quad * 4 + r;
            int col = bn + wn + j * 16 + l16;
            out[(size_t)row * N + col] = acc[i][j][r] + bias[col];
        }
}

// ---------------- V[bh][s][d] -> Vt[bh][d][s] ----------------
__global__ void transV(const bf16* __restrict__ V, bf16* __restrict__ Vt) {
    __shared__ __align__(16) bf16 T[64][72];
    int s0 = blockIdx.x * 64;
    int bh = blockIdx.y;
    const bf16* Vp = V + ((size_t)bh * S_ + s0) * DH_;
    bf16* Vtp = Vt + (size_t)bh * DH_ * S_;
    int t = threadIdx.x;
    #pragma unroll
    for (int p = 0; p < 2; ++p) {
        int r = (t >> 3) + p * 32;
        int c = (t & 7) * 8;
        bf16x8 v = *(const bf16x8*)(Vp + (size_t)r * DH_ + c);
        #pragma unroll
        for (int j = 0; j < 8; ++j) T[c + j][r] = v[j];
    }
    __syncthreads();
    #pragma unroll
    for (int p = 0; p < 2; ++p) {
        int d = (t >> 3) + p * 32;
        int c = (t & 7) * 8;
        bf16x8 v;
        #pragma unroll
        for (int j = 0; j < 8; ++j) v[j] = T[d][c + j];
        *(bf16x8*)(Vtp + (size_t)d * S_ + s0 + c) = v;
    }
}

// ---------------- flash attention v2: 1 wave/block, 32 q-rows, no-max softmax ----------------
// grid (32 bh, 64 tiles), block 64. Q,K [bh][s][d]; Vt [bh][d][s]; O [b*s][NDH] bf16
__global__ void flash2(const bf16* __restrict__ Q, const bf16* __restrict__ K,
                       const bf16* __restrict__ Vt, bf16* __restrict__ O) {
    int bh = blockIdx.x;
    int b = bh >> 4, h = bh & 15;
    int tile = 63 - (int)blockIdx.y;     // longest jobs dispatch first
    int q0 = tile * 32;
    int lane = threadIdx.x;
    int quad = lane >> 4, l16 = lane & 15;

    __shared__ __align__(16) bf16 P[2][16][72];

    const bf16* Qb = Q + (size_t)bh * S_ * DH_;
    const bf16* Kb = K + (size_t)bh * S_ * DH_;
    const bf16* Vb = Vt + (size_t)bh * DH_ * S_;

    bf16x8 qf[2][2];
    #pragma unroll
    for (int s = 0; s < 2; ++s) {
        const bf16* qp = Qb + (size_t)(q0 + s * 16 + l16) * DH_ + quad * 8;
        qf[s][0] = *(const bf16x8*)(qp);
        qf[s][1] = *(const bf16x8*)(qp + 32);
    }

    bf16x8 ones;
    #pragma unroll
    for (int j = 0; j < 8; ++j) ones[j] = (l16 == 0) ? (bf16)1.0f : (bf16)0.0f;

    f32x4 oacc[2][4] = {};
    f32x4 lacc[2] = {};

    int nkt = tile / 2 + 1;
    for (int kt = 0; kt < nkt; ++kt) {
        int kv0 = kt * 64;
        bf16x8 kf[4][2];
        #pragma unroll
        for (int ns = 0; ns < 4; ++ns) {
            const bf16* kp = Kb + (size_t)(kv0 + ns * 16 + l16) * DH_ + quad * 8;
            kf[ns][0] = *(const bf16x8*)(kp);
            kf[ns][1] = *(const bf16x8*)(kp + 32);
        }
        f32x4 sacc[2][4] = {};
        #pragma unroll
        for (int s = 0; s < 2; ++s)
          #pragma unroll
          for (int ns = 0; ns < 4; ++ns) {
            sacc[s][ns] = __builtin_amdgcn_mfma_f32_16x16x32_bf16(qf[s][0], kf[ns][0], sacc[s][ns], 0, 0, 0);
            sacc[s][ns] = __builtin_amdgcn_mfma_f32_16x16x32_bf16(qf[s][1], kf[ns][1], sacc[s][ns], 0, 0, 0);
          }
        bool diag = (kt == nkt - 1);
        #pragma unroll
        for (int s = 0; s < 2; ++s)
          #pragma unroll
          for (int ns = 0; ns < 4; ++ns)
            #pragma unroll
            for (int r = 0; r < 4; ++r) {
                float p = __expf(sacc[s][ns][r] * 0.125f);
                if (diag) {
                    int kv = kv0 + ns * 16 + l16;
                    int qq = q0 + s * 16 + quad * 4 + r;
                    if (kv > qq) p = 0.f;
                }
                P[s][quad * 4 + r][ns * 16 + l16] = (bf16)p;
            }
        #pragma unroll
        for (int ks = 0; ks < 2; ++ks) {
            bf16x8 pf0 = *(const bf16x8*)&P[0][l16][ks * 32 + quad * 8];
            bf16x8 pf1 = *(const bf16x8*)&P[1][l16][ks * 32 + quad * 8];
            lacc[0] = __builtin_amdgcn_mfma_f32_16x16x32_bf16(pf0, ones, lacc[0], 0, 0, 0);
            lacc[1] = __builtin_amdgcn_mfma_f32_16x16x32_bf16(pf1, ones, lacc[1], 0, 0, 0);
            #pragma unroll
            for (int ds = 0; ds < 4; ++ds) {
                bf16x8 vf = *(const bf16x8*)(Vb + (size_t)(ds * 16 + l16) * S_ + kv0 + ks * 32 + quad * 8);
                oacc[0][ds] = __builtin_amdgcn_mfma_f32_16x16x32_bf16(pf0, vf, oacc[0][ds], 0, 0, 0);
                oacc[1][ds] = __builtin_amdgcn_mfma_f32_16x16x32_bf16(pf1, vf, oacc[1][ds], 0, 0, 0);
            }
        }
    }

    #pragma unroll
    for (int s = 0; s < 2; ++s)
      #pragma unroll
      for (int r = 0; r < 4; ++r) {
        float l = __shfl(lacc[s][r], lane & 48);
        float inv = 1.0f / l;
        int qq = q0 + s * 16 + quad * 4 + r;
        bf16* Op = O + ((size_t)b * S_ + qq) * NDH + h * DH_;
        #pragma unroll
        for (int ds = 0; ds < 4; ++ds)
            Op[ds * 16 + l16] = (bf16)(oacc[s][ds][r] * inv);
      }
}

extern "C" void kernel_launch(void* const* d_in, const int* in_sizes, int n_in,
                              void* d_out, int out_size, void* d_ws, size_t ws_size,
                              hipStream_t stream) {
    const float* x  = (const float*)d_in[0];
    const float* Wq = (const float*)d_in[1];
    const float* bq = (const float*)d_in[2];
    const float* Wk = (const float*)d_in[3];
    const float* bk = (const float*)d_in[4];
    const float* Wv = (const float*)d_in[5];
    const float* bv = (const float*)d_in[6];
    const float* Wo = (const float*)d_in[7];
    const float* bo = (const float*)d_in[8];
    float* out = (float*)d_out;

    bf16* ws = (bf16*)d_ws;
    const size_t M1 = (size_t)1024 * 1024;
    bf16* xb   = ws;                    // 4M
    bf16* WqkvT = ws + 4 * M1;          // 3M contiguous (WqT|WkT|WvT)
    bf16* WoT  = ws + 7 * M1;
    bf16* Qw   = ws + 8 * M1;           // Q|K|V contiguous, 4M each
    bf16* Vw   = ws + 16 * M1;
    bf16* Vtw  = ws + 20 * M1;
    bf16* Ow   = ws + 24 * M1;

    int nx = BS_ * D_;
    cast_bf16<<<nx / 4 / 256, 256, 0, stream>>>(x, xb, nx);
    dim3 tw(32, 32);
    transW<<<tw, 256, 0, stream>>>(Wq, WqkvT, D_, NDH);
    transW<<<tw, 256, 0, stream>>>(Wk, WqkvT + M1, D_, NDH);
    transW<<<tw, 256, 0, stream>>>(Wv, WqkvT + 2 * M1, D_, NDH);
    transW<<<tw, 256, 0, stream>>>(Wo, WoT, NDH, D_);

    qkv_gemm<<<dim3(3072 / 128, BS_ / 128), 256, 0, stream>>>(xb, WqkvT, bq, bk, bv, Qw);

    transV<<<dim3(S_ / 64, B_ * H_), 256, 0, stream>>>(Vw, Vtw);

    flash2<<<dim3(B_ * H_, 64), 64, 0, stream>>>(Qw, Qw + PER, Vtw, Ow);

    gemm_bt<<<dim3(D_ / GBN, BS_ / GBM), 256, 0, stream>>>(Ow, WoT, bo, out, BS_, D_, NDH);
}

// Round 4
// 224.231 us; speedup vs baseline: 24.3346x; 1.1975x over previous
//
#include <hip/hip_runtime.h>

#define B_  2
#define S_  2048
#define D_  1024
#define H_  16
#define DH_ 64
#define NDH (H_*DH_)   // 1024
#define BS_ (B_*S_)    // 4096
#define PER ((size_t)B_*H_*S_*DH_)   // 4M elements

typedef __bf16 bf16;
typedef bf16 bf16x8 __attribute__((ext_vector_type(8)));
typedef bf16 bf16x4 __attribute__((ext_vector_type(4)));
typedef float f32x4 __attribute__((ext_vector_type(4)));

#define AS1 __attribute__((address_space(1)))
#define AS3 __attribute__((address_space(3)))
__device__ inline void gld16(const bf16* g, bf16* l) {
    __builtin_amdgcn_global_load_lds((const AS1 void*)g, (AS3 void*)l, 16, 0, 0);
}

// ---------------- cast fp32 -> bf16 ----------------
__global__ void cast_bf16(const float* __restrict__ in, bf16* __restrict__ out, int n) {
    int i = (blockIdx.x * blockDim.x + threadIdx.x) * 4;
    if (i < n) {
        float4 v = *(const float4*)(in + i);
        bf16x4 o = { (bf16)v.x, (bf16)v.y, (bf16)v.z, (bf16)v.w };
        *(bf16x4*)(out + i) = o;
    }
}

// ---------------- transpose-cast 4x W[1024][1024] fp32 -> Wt[1024][1024] bf16 ----------------
__global__ void transW4(const float* __restrict__ W0, const float* __restrict__ W1,
                        const float* __restrict__ W2, const float* __restrict__ W3,
                        bf16* __restrict__ T0, bf16* __restrict__ T1,
                        bf16* __restrict__ T2, bf16* __restrict__ T3) {
    int z = blockIdx.z;
    const float* W = (z == 0) ? W0 : (z == 1) ? W1 : (z == 2) ? W2 : W3;
    bf16* Wt = (z == 0) ? T0 : (z == 1) ? T1 : (z == 2) ? T2 : T3;
    __shared__ float T[32][33];
    int k0 = blockIdx.y * 32, n0 = blockIdx.x * 32;
    int t = threadIdx.x;
    int r = t >> 3, c = (t & 7) * 4;
    float4 v = *(const float4*)(W + (size_t)(k0 + r) * 1024 + n0 + c);
    T[c + 0][r] = v.x; T[c + 1][r] = v.y; T[c + 2][r] = v.z; T[c + 3][r] = v.w;
    __syncthreads();
    bf16x4 o = { (bf16)T[r][c], (bf16)T[r][c + 1], (bf16)T[r][c + 2], (bf16)T[r][c + 3] };
    *(bf16x4*)(Wt + (size_t)(n0 + r) * 1024 + k0 + c) = o;
}

// ---------------- fused QKV GEMM: 128x128 tile, global_load_lds ----------------
// A [4096][1024] bf16, Bt [3072][1024] bf16 (Wq|Wk|Wv transposed).
// Q,K -> [B][H][S][DH] at Qout + qkv*PER;  V -> transposed [B][H][DH][S] at Vt.
__global__ __launch_bounds__(256) void qkv_gemm(
        const bf16* __restrict__ A, const bf16* __restrict__ Bt,
        const float* __restrict__ bq, const float* __restrict__ bk,
        const float* __restrict__ bv, bf16* __restrict__ Qout, bf16* __restrict__ Vt) {
    __shared__ __align__(16) bf16 As[128 * 32];
    __shared__ __align__(16) bf16 Bs[128 * 32];
    int tid = threadIdx.x, wave = tid >> 6, lane = tid & 63;
    int quad = lane >> 4, l16 = lane & 15;
    int bm = blockIdx.y * 128, bn = blockIdx.x * 128;
    int wm = (wave >> 1) * 64, wn = (wave & 1) * 64;

    int sr = lane >> 2, sc = (lane & 3) * 8;
    const bf16* Ag0 = A + (size_t)(bm + (wave * 2 + 0) * 16 + sr) * 1024 + sc;
    const bf16* Ag1 = A + (size_t)(bm + (wave * 2 + 1) * 16 + sr) * 1024 + sc;
    const bf16* Bg0 = Bt + (size_t)(bn + (wave * 2 + 0) * 16 + sr) * 1024 + sc;
    const bf16* Bg1 = Bt + (size_t)(bn + (wave * 2 + 1) * 16 + sr) * 1024 + sc;
    bf16* Al0 = &As[(wave * 2 + 0) * 512];
    bf16* Al1 = &As[(wave * 2 + 1) * 512];
    bf16* Bl0 = &Bs[(wave * 2 + 0) * 512];
    bf16* Bl1 = &Bs[(wave * 2 + 1) * 512];

    f32x4 acc[4][4] = {};

    for (int k0 = 0; k0 < 1024; k0 += 32) {
        gld16(Ag0 + k0, Al0);
        gld16(Ag1 + k0, Al1);
        gld16(Bg0 + k0, Bl0);
        gld16(Bg1 + k0, Bl1);
        __syncthreads();
        bf16x8 af[4], bfr[4];
        #pragma unroll
        for (int i = 0; i < 4; ++i)
            af[i] = *(const bf16x8*)&As[(wm + i * 16 + l16) * 32 + quad * 8];
        #pragma unroll
        for (int j = 0; j < 4; ++j)
            bfr[j] = *(const bf16x8*)&Bs[(wn + j * 16 + l16) * 32 + quad * 8];
        #pragma unroll
        for (int i = 0; i < 4; ++i)
          #pragma unroll
          for (int j = 0; j < 4; ++j)
            acc[i][j] = __builtin_amdgcn_mfma_f32_16x16x32_bf16(af[i], bfr[j], acc[i][j], 0, 0, 0);
        __syncthreads();
    }

    #pragma unroll
    for (int i = 0; i < 4; ++i)
      #pragma unroll
      for (int j = 0; j < 4; ++j) {
        int col = bn + wn + j * 16 + l16;
        float bias = (col < 1024) ? bq[col] : (col < 2048) ? bk[col - 1024] : bv[col - 2048];
        int qkv = col >> 10, cw = col & 1023;
        int hh = cw >> 6, d = cw & 63;
        int row0 = bm + wm + i * 16 + quad * 4;
        int bb = row0 >> 11, s0 = row0 & 2047;
        if (qkv < 2) {
            #pragma unroll
            for (int r = 0; r < 4; ++r)
                Qout[(size_t)qkv * PER + (((size_t)bb * H_ + hh) * S_ + s0 + r) * DH_ + d] =
                    (bf16)(acc[i][j][r] + bias);
        } else {
            bf16x4 pack;
            #pragma unroll
            for (int r = 0; r < 4; ++r) pack[r] = (bf16)(acc[i][j][r] + bias);
            *(bf16x4*)&Vt[(((size_t)bb * H_ + hh) * DH_ + d) * S_ + s0] = pack;
        }
      }
}

// ---------------- output-projection GEMM: 128x128 tile, fp32 out + bias ----------------
__global__ __launch_bounds__(256) void gemm128f(
        const bf16* __restrict__ A, const bf16* __restrict__ Bt,
        const float* __restrict__ bias, float* __restrict__ out) {
    __shared__ __align__(16) bf16 As[128 * 32];
    __shared__ __align__(16) bf16 Bs[128 * 32];
    int tid = threadIdx.x, wave = tid >> 6, lane = tid & 63;
    int quad = lane >> 4, l16 = lane & 15;
    int bm = blockIdx.y * 128, bn = blockIdx.x * 128;
    int wm = (wave >> 1) * 64, wn = (wave & 1) * 64;

    int sr = lane >> 2, sc = (lane & 3) * 8;
    const bf16* Ag0 = A + (size_t)(bm + (wave * 2 + 0) * 16 + sr) * 1024 + sc;
    const bf16* Ag1 = A + (size_t)(bm + (wave * 2 + 1) * 16 + sr) * 1024 + sc;
    const bf16* Bg0 = Bt + (size_t)(bn + (wave * 2 + 0) * 16 + sr) * 1024 + sc;
    const bf16* Bg1 = Bt + (size_t)(bn + (wave * 2 + 1) * 16 + sr) * 1024 + sc;
    bf16* Al0 = &As[(wave * 2 + 0) * 512];
    bf16* Al1 = &As[(wave * 2 + 1) * 512];
    bf16* Bl0 = &Bs[(wave * 2 + 0) * 512];
    bf16* Bl1 = &Bs[(wave * 2 + 1) * 512];

    f32x4 acc[4][4] = {};

    for (int k0 = 0; k0 < 1024; k0 += 32) {
        gld16(Ag0 + k0, Al0);
        gld16(Ag1 + k0, Al1);
        gld16(Bg0 + k0, Bl0);
        gld16(Bg1 + k0, Bl1);
        __syncthreads();
        bf16x8 af[4], bfr[4];
        #pragma unroll
        for (int i = 0; i < 4; ++i)
            af[i] = *(const bf16x8*)&As[(wm + i * 16 + l16) * 32 + quad * 8];
        #pragma unroll
        for (int j = 0; j < 4; ++j)
            bfr[j] = *(const bf16x8*)&Bs[(wn + j * 16 + l16) * 32 + quad * 8];
        #pragma unroll
        for (int i = 0; i < 4; ++i)
          #pragma unroll
          for (int j = 0; j < 4; ++j)
            acc[i][j] = __builtin_amdgcn_mfma_f32_16x16x32_bf16(af[i], bfr[j], acc[i][j], 0, 0, 0);
        __syncthreads();
    }

    #pragma unroll
    for (int i = 0; i < 4; ++i)
      #pragma unroll
      for (int j = 0; j < 4; ++j) {
        int col = bn + wn + j * 16 + l16;
        float b = bias[col];
        #pragma unroll
        for (int r = 0; r < 4; ++r) {
            int row = bm + wm + i * 16 + quad * 4 + r;
            out[(size_t)row * 1024 + col] = acc[i][j][r] + b;
        }
      }
}

// ---------------- flash attention v3: split-kv, 4 waves/block ----------------
// grid (32 bh, 64 tiles), 256 thr. Q,K [bh][s][d]; Vt [bh][d][s]; O [b*s][NDH] bf16.
// No-max softmax: partial (O,l) over disjoint kv ranges sum directly.
__global__ __launch_bounds__(256) void flash3(
        const bf16* __restrict__ Q, const bf16* __restrict__ K,
        const bf16* __restrict__ Vt, bf16* __restrict__ O) {
    int bh = blockIdx.x;
    int b = bh >> 4, h = bh & 15;
    int tile = 63 - (int)blockIdx.y;     // longest jobs dispatch first
    int q0 = tile * 32;
    int tid = threadIdx.x;
    int wave = tid >> 6, lane = tid & 63;
    int quad = lane >> 4, l16 = lane & 15;

    // P (per-wave, loop phase) aliases redO (reduction phase)
    __shared__ __align__(16) char smem[4 * 2 * 16 * 72 * 2];   // 18432 B
    bf16 (*P)[2][16][72] = reinterpret_cast<bf16 (*)[2][16][72]>(smem);
    float (*redO)[4][64][4] = reinterpret_cast<float (*)[4][64][4]>(smem); // 16384 B
    __shared__ float redL[4][2][4][4];

    const bf16* Qb = Q + (size_t)bh * S_ * DH_;
    const bf16* Kb = K + (size_t)bh * S_ * DH_;
    const bf16* Vb = Vt + (size_t)bh * DH_ * S_;

    bf16x8 qf[2][2];
    #pragma unroll
    for (int s = 0; s < 2; ++s) {
        const bf16* qp = Qb + (size_t)(q0 + s * 16 + l16) * DH_ + quad * 8;
        qf[s][0] = *(const bf16x8*)(qp);
        qf[s][1] = *(const bf16x8*)(qp + 32);
    }

    bf16x8 ones;
    #pragma unroll
    for (int j = 0; j < 8; ++j) ones[j] = (l16 == 0) ? (bf16)1.0f : (bf16)0.0f;

    f32x4 oacc[2][4] = {};
    f32x4 lacc[2] = {};

    int nkt = tile / 2 + 1;
    for (int kt = wave; kt < nkt; kt += 4) {
        int kv0 = kt * 64;
        bf16x8 kf[4][2];
        #pragma unroll
        for (int ns = 0; ns < 4; ++ns) {
            const bf16* kp = Kb + (size_t)(kv0 + ns * 16 + l16) * DH_ + quad * 8;
            kf[ns][0] = *(const bf16x8*)(kp);
            kf[ns][1] = *(const bf16x8*)(kp + 32);
        }
        f32x4 sacc[2][4] = {};
        #pragma unroll
        for (int s = 0; s < 2; ++s)
          #pragma unroll
          for (int ns = 0; ns < 4; ++ns) {
            sacc[s][ns] = __builtin_amdgcn_mfma_f32_16x16x32_bf16(qf[s][0], kf[ns][0], sacc[s][ns], 0, 0, 0);
            sacc[s][ns] = __builtin_amdgcn_mfma_f32_16x16x32_bf16(qf[s][1], kf[ns][1], sacc[s][ns], 0, 0, 0);
          }
        bool diag = (kt == nkt - 1);
        #pragma unroll
        for (int s = 0; s < 2; ++s)
          #pragma unroll
          for (int ns = 0; ns < 4; ++ns)
            #pragma unroll
            for (int r = 0; r < 4; ++r) {
                float p = __expf(sacc[s][ns][r] * 0.125f);
                if (diag) {
                    int kv = kv0 + ns * 16 + l16;
                    int qq = q0 + s * 16 + quad * 4 + r;
                    if (kv > qq) p = 0.f;
                }
                P[wave][s][quad * 4 + r][ns * 16 + l16] = (bf16)p;
            }
        #pragma unroll
        for (int ks = 0; ks < 2; ++ks) {
            bf16x8 pf0 = *(const bf16x8*)&P[wave][0][l16][ks * 32 + quad * 8];
            bf16x8 pf1 = *(const bf16x8*)&P[wave][1][l16][ks * 32 + quad * 8];
            lacc[0] = __builtin_amdgcn_mfma_f32_16x16x32_bf16(pf0, ones, lacc[0], 0, 0, 0);
            lacc[1] = __builtin_amdgcn_mfma_f32_16x16x32_bf16(pf1, ones, lacc[1], 0, 0, 0);
            #pragma unroll
            for (int ds = 0; ds < 4; ++ds) {
                bf16x8 vf = *(const bf16x8*)(Vb + (size_t)(ds * 16 + l16) * S_ + kv0 + ks * 32 + quad * 8);
                oacc[0][ds] = __builtin_amdgcn_mfma_f32_16x16x32_bf16(pf0, vf, oacc[0][ds], 0, 0, 0);
                oacc[1][ds] = __builtin_amdgcn_mfma_f32_16x16x32_bf16(pf1, vf, oacc[1][ds], 0, 0, 0);
            }
        }
    }

    // cross-wave reduction (pure sums; no-max softmax => no rescale needed)
    if (l16 == 0) {
        #pragma unroll
        for (int s = 0; s < 2; ++s)
          #pragma unroll
          for (int r = 0; r < 4; ++r)
            redL[wave][s][quad][r] = lacc[s][r];
    }
    #pragma unroll
    for (int s = 0; s < 2; ++s) {
        __syncthreads();   // waves done with P (s=0) / prior reduce reads (s=1)
        #pragma unroll
        for (int ds = 0; ds < 4; ++ds)
            *(f32x4*)&redO[wave][ds][lane][0] = oacc[s][ds];
        __syncthreads();
        f32x4 osum = {};
        #pragma unroll
        for (int w = 0; w < 4; ++w)
            osum += *(const f32x4*)&redO[w][wave][lane][0];
        #pragma unroll
        for (int r = 0; r < 4; ++r) {
            float lsum = redL[0][s][quad][r] + redL[1][s][quad][r]
                       + redL[2][s][quad][r] + redL[3][s][quad][r];
            int qq = q0 + s * 16 + quad * 4 + r;
            O[((size_t)b * S_ + qq) * NDH + h * DH_ + wave * 16 + l16] = (bf16)(osum[r] / lsum);
        }
    }
}

extern "C" void kernel_launch(void* const* d_in, const int* in_sizes, int n_in,
                              void* d_out, int out_size, void* d_ws, size_t ws_size,
                              hipStream_t stream) {
    const float* x  = (const float*)d_in[0];
    const float* Wq = (const float*)d_in[1];
    const float* bq = (const float*)d_in[2];
    const float* Wk = (const float*)d_in[3];
    const float* bk = (const float*)d_in[4];
    const float* Wv = (const float*)d_in[5];
    const float* bv = (const float*)d_in[6];
    const float* Wo = (const float*)d_in[7];
    const float* bo = (const float*)d_in[8];
    float* out = (float*)d_out;

    bf16* ws = (bf16*)d_ws;
    const size_t M1 = (size_t)1024 * 1024;
    bf16* xb    = ws;                   // 4M
    bf16* WqkvT = ws + 4 * M1;          // 3M contiguous (WqT|WkT|WvT)
    bf16* WoT   = ws + 7 * M1;          // 1M
    bf16* Qw    = ws + 8 * M1;          // Q|K contiguous, 4M each
    bf16* Vtw   = ws + 16 * M1;         // 4M ([bh][d][s])
    bf16* Ow    = ws + 20 * M1;         // 4M

    int nx = BS_ * D_;
    cast_bf16<<<nx / 4 / 256, 256, 0, stream>>>(x, xb, nx);
    transW4<<<dim3(32, 32, 4), 256, 0, stream>>>(Wq, Wk, Wv, Wo,
                                                 WqkvT, WqkvT + M1, WqkvT + 2 * M1, WoT);

    qkv_gemm<<<dim3(3072 / 128, BS_ / 128), 256, 0, stream>>>(xb, WqkvT, bq, bk, bv, Qw, Vtw);

    flash3<<<dim3(B_ * H_, 64), 256, 0, stream>>>(Qw, Qw + PER, Vtw, Ow);

    gemm128f<<<dim3(1024 / 128, BS_ / 128), 256, 0, stream>>>(Ow, WoT, bo, out);
}

// Round 5
// 219.488 us; speedup vs baseline: 24.8604x; 1.0216x over previous
//
#include <hip/hip_runtime.h>

#define B_  2
#define S_  2048
#define D_  1024
#define H_  16
#define DH_ 64
#define NDH (H_*DH_)   // 1024
#define BS_ (B_*S_)    // 4096
#define PER ((size_t)B_*H_*S_*DH_)   // 4M elements

typedef __bf16 bf16;
typedef bf16 bf16x8 __attribute__((ext_vector_type(8)));
typedef bf16 bf16x4 __attribute__((ext_vector_type(4)));
typedef float f32x4 __attribute__((ext_vector_type(4)));

#define AS1 __attribute__((address_space(1)))
#define AS3 __attribute__((address_space(3)))
__device__ inline void gld16(const bf16* g, bf16* l) {
    __builtin_amdgcn_global_load_lds((const AS1 void*)g, (AS3 void*)l, 16, 0, 0);
}

// ---------------- fused prep: cast x -> bf16  +  transpose-cast 4 weight mats ----------------
// blocks [0,4096): cast;  [4096, 8192): 4x transW (1024 blocks each)
__global__ __launch_bounds__(256) void prep(
        const float* __restrict__ x,
        const float* __restrict__ W0, const float* __restrict__ W1,
        const float* __restrict__ W2, const float* __restrict__ W3,
        bf16* __restrict__ xb, bf16* __restrict__ T0, bf16* __restrict__ T1,
        bf16* __restrict__ T2, bf16* __restrict__ T3) {
    __shared__ float T[32][33];
    int bid = blockIdx.x, t = threadIdx.x;
    if (bid < 4096) {
        int i = (bid * 256 + t) * 4;
        float4 v = *(const float4*)(x + i);
        bf16x4 o = { (bf16)v.x, (bf16)v.y, (bf16)v.z, (bf16)v.w };
        *(bf16x4*)(xb + i) = o;
        return;
    }
    int r2 = bid - 4096;
    int z = r2 >> 10, w = r2 & 1023;
    const float* W = (z == 0) ? W0 : (z == 1) ? W1 : (z == 2) ? W2 : W3;
    bf16* Wt = (z == 0) ? T0 : (z == 1) ? T1 : (z == 2) ? T2 : T3;
    int k0 = (w >> 5) * 32, n0 = (w & 31) * 32;
    int r = t >> 3, c = (t & 7) * 4;
    float4 v = *(const float4*)(W + (size_t)(k0 + r) * 1024 + n0 + c);
    T[c + 0][r] = v.x; T[c + 1][r] = v.y; T[c + 2][r] = v.z; T[c + 3][r] = v.w;
    __syncthreads();
    bf16x4 o = { (bf16)T[r][c], (bf16)T[r][c + 1], (bf16)T[r][c + 2], (bf16)T[r][c + 3] };
    *(bf16x4*)(Wt + (size_t)(n0 + r) * 1024 + k0 + c) = o;
}

// ---------------- fused QKV GEMM: 128x128 tile, global_load_lds ----------------
// A [4096][1024] bf16, Bt [3072][1024] bf16 (Wq|Wk|Wv transposed).
// Q,K -> [B][H][S][DH] at Qout + qkv*PER;  V -> transposed [B][H][DH][S] at Vt.
__global__ __launch_bounds__(256) void qkv_gemm(
        const bf16* __restrict__ A, const bf16* __restrict__ Bt,
        const float* __restrict__ bq, const float* __restrict__ bk,
        const float* __restrict__ bv, bf16* __restrict__ Qout, bf16* __restrict__ Vt) {
    __shared__ __align__(16) bf16 As[128 * 32];
    __shared__ __align__(16) bf16 Bs[128 * 32];
    int tid = threadIdx.x, wave = tid >> 6, lane = tid & 63;
    int quad = lane >> 4, l16 = lane & 15;
    int bm = blockIdx.y * 128, bn = blockIdx.x * 128;
    int wm = (wave >> 1) * 64, wn = (wave & 1) * 64;

    int sr = lane >> 2, sc = (lane & 3) * 8;
    const bf16* Ag0 = A + (size_t)(bm + (wave * 2 + 0) * 16 + sr) * 1024 + sc;
    const bf16* Ag1 = A + (size_t)(bm + (wave * 2 + 1) * 16 + sr) * 1024 + sc;
    const bf16* Bg0 = Bt + (size_t)(bn + (wave * 2 + 0) * 16 + sr) * 1024 + sc;
    const bf16* Bg1 = Bt + (size_t)(bn + (wave * 2 + 1) * 16 + sr) * 1024 + sc;
    bf16* Al0 = &As[(wave * 2 + 0) * 512];
    bf16* Al1 = &As[(wave * 2 + 1) * 512];
    bf16* Bl0 = &Bs[(wave * 2 + 0) * 512];
    bf16* Bl1 = &Bs[(wave * 2 + 1) * 512];

    f32x4 acc[4][4] = {};

    for (int k0 = 0; k0 < 1024; k0 += 32) {
        gld16(Ag0 + k0, Al0);
        gld16(Ag1 + k0, Al1);
        gld16(Bg0 + k0, Bl0);
        gld16(Bg1 + k0, Bl1);
        __syncthreads();
        bf16x8 af[4], bfr[4];
        #pragma unroll
        for (int i = 0; i < 4; ++i)
            af[i] = *(const bf16x8*)&As[(wm + i * 16 + l16) * 32 + quad * 8];
        #pragma unroll
        for (int j = 0; j < 4; ++j)
            bfr[j] = *(const bf16x8*)&Bs[(wn + j * 16 + l16) * 32 + quad * 8];
        #pragma unroll
        for (int i = 0; i < 4; ++i)
          #pragma unroll
          for (int j = 0; j < 4; ++j)
            acc[i][j] = __builtin_amdgcn_mfma_f32_16x16x32_bf16(af[i], bfr[j], acc[i][j], 0, 0, 0);
        __syncthreads();
    }

    #pragma unroll
    for (int i = 0; i < 4; ++i)
      #pragma unroll
      for (int j = 0; j < 4; ++j) {
        int col = bn + wn + j * 16 + l16;
        float bias = (col < 1024) ? bq[col] : (col < 2048) ? bk[col - 1024] : bv[col - 2048];
        int qkv = col >> 10, cw = col & 1023;
        int hh = cw >> 6, d = cw & 63;
        int row0 = bm + wm + i * 16 + quad * 4;
        int bb = row0 >> 11, s0 = row0 & 2047;
        if (qkv < 2) {
            #pragma unroll
            for (int r = 0; r < 4; ++r)
                Qout[(size_t)qkv * PER + (((size_t)bb * H_ + hh) * S_ + s0 + r) * DH_ + d] =
                    (bf16)(acc[i][j][r] + bias);
        } else {
            bf16x4 pack;
            #pragma unroll
            for (int r = 0; r < 4; ++r) pack[r] = (bf16)(acc[i][j][r] + bias);
            *(bf16x4*)&Vt[(((size_t)bb * H_ + hh) * DH_ + d) * S_ + s0] = pack;
        }
      }
}

// ---------------- output-projection GEMM: 128x128 tile, fp32 out + bias ----------------
__global__ __launch_bounds__(256) void gemm128f(
        const bf16* __restrict__ A, const bf16* __restrict__ Bt,
        const float* __restrict__ bias, float* __restrict__ out) {
    __shared__ __align__(16) bf16 As[128 * 32];
    __shared__ __align__(16) bf16 Bs[128 * 32];
    int tid = threadIdx.x, wave = tid >> 6, lane = tid & 63;
    int quad = lane >> 4, l16 = lane & 15;
    int bm = blockIdx.y * 128, bn = blockIdx.x * 128;
    int wm = (wave >> 1) * 64, wn = (wave & 1) * 64;

    int sr = lane >> 2, sc = (lane & 3) * 8;
    const bf16* Ag0 = A + (size_t)(bm + (wave * 2 + 0) * 16 + sr) * 1024 + sc;
    const bf16* Ag1 = A + (size_t)(bm + (wave * 2 + 1) * 16 + sr) * 1024 + sc;
    const bf16* Bg0 = Bt + (size_t)(bn + (wave * 2 + 0) * 16 + sr) * 1024 + sc;
    const bf16* Bg1 = Bt + (size_t)(bn + (wave * 2 + 1) * 16 + sr) * 1024 + sc;
    bf16* Al0 = &As[(wave * 2 + 0) * 512];
    bf16* Al1 = &As[(wave * 2 + 1) * 512];
    bf16* Bl0 = &Bs[(wave * 2 + 0) * 512];
    bf16* Bl1 = &Bs[(wave * 2 + 1) * 512];

    f32x4 acc[4][4] = {};

    for (int k0 = 0; k0 < 1024; k0 += 32) {
        gld16(Ag0 + k0, Al0);
        gld16(Ag1 + k0, Al1);
        gld16(Bg0 + k0, Bl0);
        gld16(Bg1 + k0, Bl1);
        __syncthreads();
        bf16x8 af[4], bfr[4];
        #pragma unroll
        for (int i = 0; i < 4; ++i)
            af[i] = *(const bf16x8*)&As[(wm + i * 16 + l16) * 32 + quad * 8];
        #pragma unroll
        for (int j = 0; j < 4; ++j)
            bfr[j] = *(const bf16x8*)&Bs[(wn + j * 16 + l16) * 32 + quad * 8];
        #pragma unroll
        for (int i = 0; i < 4; ++i)
          #pragma unroll
          for (int j = 0; j < 4; ++j)
            acc[i][j] = __builtin_amdgcn_mfma_f32_16x16x32_bf16(af[i], bfr[j], acc[i][j], 0, 0, 0);
        __syncthreads();
    }

    #pragma unroll
    for (int i = 0; i < 4; ++i)
      #pragma unroll
      for (int j = 0; j < 4; ++j) {
        int col = bn + wn + j * 16 + l16;
        float b = bias[col];
        #pragma unroll
        for (int r = 0; r < 4; ++r) {
            int row = bm + wm + i * 16 + quad * 4 + r;
            out[(size_t)row * 1024 + col] = acc[i][j][r] + b;
        }
      }
}

// ---------------- flash attention v4: tile-paired, split-kv, 4 waves/block ----------------
// grid (32 bh, 32 pairs), 256 thr. Block handles q-tiles {p, 63-p}: uniform ~33 kt iters.
// No-max softmax: partial (O,l) over disjoint kv ranges sum directly.
__global__ __launch_bounds__(256) void flash4(
        const bf16* __restrict__ Q, const bf16* __restrict__ K,
        const bf16* __restrict__ Vt, bf16* __restrict__ O) {
    int bh = blockIdx.x;
    int b = bh >> 4, h = bh & 15;
    int pr = blockIdx.y;                 // 0..31
    int tid = threadIdx.x;
    int wave = tid >> 6, lane = tid & 63;
    int quad = lane >> 4, l16 = lane & 15;

    // P (per-wave, loop phase) aliases redO (reduction phase)
    __shared__ __align__(16) char smem[4 * 2 * 16 * 72 * 2];   // 18432 B
    bf16 (*P)[2][16][72] = reinterpret_cast<bf16 (*)[2][16][72]>(smem);
    float (*redO)[4][64][4] = reinterpret_cast<float (*)[4][64][4]>(smem); // 16384 B
    __shared__ float redL[4][2][4][4];

    const bf16* Qb = Q + (size_t)bh * S_ * DH_;
    const bf16* Kb = K + (size_t)bh * S_ * DH_;
    const bf16* Vb = Vt + (size_t)bh * DH_ * S_;

    bf16x8 ones;
    #pragma unroll
    for (int j = 0; j < 8; ++j) ones[j] = (l16 == 0) ? (bf16)1.0f : (bf16)0.0f;

    for (int half = 0; half < 2; ++half) {
        int tile = half ? (63 - pr) : pr;
        int q0 = tile * 32;

        bf16x8 qf[2][2];
        #pragma unroll
        for (int s = 0; s < 2; ++s) {
            const bf16* qp = Qb + (size_t)(q0 + s * 16 + l16) * DH_ + quad * 8;
            qf[s][0] = *(const bf16x8*)(qp);
            qf[s][1] = *(const bf16x8*)(qp + 32);
        }

        f32x4 oacc[2][4] = {};
        f32x4 lacc[2] = {};

        int nkt = tile / 2 + 1;
        for (int kt = wave; kt < nkt; kt += 4) {
            int kv0 = kt * 64;
            bf16x8 kf[4][2];
            #pragma unroll
            for (int ns = 0; ns < 4; ++ns) {
                const bf16* kp = Kb + (size_t)(kv0 + ns * 16 + l16) * DH_ + quad * 8;
                kf[ns][0] = *(const bf16x8*)(kp);
                kf[ns][1] = *(const bf16x8*)(kp + 32);
            }
            f32x4 sacc[2][4] = {};
            #pragma unroll
            for (int s = 0; s < 2; ++s)
              #pragma unroll
              for (int ns = 0; ns < 4; ++ns) {
                sacc[s][ns] = __builtin_amdgcn_mfma_f32_16x16x32_bf16(qf[s][0], kf[ns][0], sacc[s][ns], 0, 0, 0);
                sacc[s][ns] = __builtin_amdgcn_mfma_f32_16x16x32_bf16(qf[s][1], kf[ns][1], sacc[s][ns], 0, 0, 0);
              }
            bool diag = (kt == nkt - 1);
            #pragma unroll
            for (int s = 0; s < 2; ++s)
              #pragma unroll
              for (int ns = 0; ns < 4; ++ns)
                #pragma unroll
                for (int r = 0; r < 4; ++r) {
                    float p = __expf(sacc[s][ns][r] * 0.125f);
                    if (diag) {
                        int kv = kv0 + ns * 16 + l16;
                        int qq = q0 + s * 16 + quad * 4 + r;
                        if (kv > qq) p = 0.f;
                    }
                    P[wave][s][quad * 4 + r][ns * 16 + l16] = (bf16)p;
                }
            #pragma unroll
            for (int ks = 0; ks < 2; ++ks) {
                bf16x8 pf0 = *(const bf16x8*)&P[wave][0][l16][ks * 32 + quad * 8];
                bf16x8 pf1 = *(const bf16x8*)&P[wave][1][l16][ks * 32 + quad * 8];
                lacc[0] = __builtin_amdgcn_mfma_f32_16x16x32_bf16(pf0, ones, lacc[0], 0, 0, 0);
                lacc[1] = __builtin_amdgcn_mfma_f32_16x16x32_bf16(pf1, ones, lacc[1], 0, 0, 0);
                #pragma unroll
                for (int ds = 0; ds < 4; ++ds) {
                    bf16x8 vf = *(const bf16x8*)(Vb + (size_t)(ds * 16 + l16) * S_ + kv0 + ks * 32 + quad * 8);
                    oacc[0][ds] = __builtin_amdgcn_mfma_f32_16x16x32_bf16(pf0, vf, oacc[0][ds], 0, 0, 0);
                    oacc[1][ds] = __builtin_amdgcn_mfma_f32_16x16x32_bf16(pf1, vf, oacc[1][ds], 0, 0, 0);
                }
            }
        }

        // cross-wave reduction (pure sums)
        if (l16 == 0) {
            #pragma unroll
            for (int s = 0; s < 2; ++s)
              #pragma unroll
              for (int r = 0; r < 4; ++r)
                redL[wave][s][quad][r] = lacc[s][r];
        }
        #pragma unroll
        for (int s = 0; s < 2; ++s) {
            __syncthreads();   // all waves done with P / prior redO reads
            #pragma unroll
            for (int ds = 0; ds < 4; ++ds)
                *(f32x4*)&redO[wave][ds][lane][0] = oacc[s][ds];
            __syncthreads();
            f32x4 osum = {};
            #pragma unroll
            for (int w = 0; w < 4; ++w)
                osum += *(const f32x4*)&redO[w][wave][lane][0];
            #pragma unroll
            for (int r = 0; r < 4; ++r) {
                float lsum = redL[0][s][quad][r] + redL[1][s][quad][r]
                           + redL[2][s][quad][r] + redL[3][s][quad][r];
                int qq = q0 + s * 16 + quad * 4 + r;
                O[((size_t)b * S_ + qq) * NDH + h * DH_ + wave * 16 + l16] = (bf16)(osum[r] / lsum);
            }
        }
        __syncthreads();   // protect P/redL reuse by next half
    }
}

extern "C" void kernel_launch(void* const* d_in, const int* in_sizes, int n_in,
                              void* d_out, int out_size, void* d_ws, size_t ws_size,
                              hipStream_t stream) {
    const float* x  = (const float*)d_in[0];
    const float* Wq = (const float*)d_in[1];
    const float* bq = (const float*)d_in[2];
    const float* Wk = (const float*)d_in[3];
    const float* bk = (const float*)d_in[4];
    const float* Wv = (const float*)d_in[5];
    const float* bv = (const float*)d_in[6];
    const float* Wo = (const float*)d_in[7];
    const float* bo = (const float*)d_in[8];
    float* out = (float*)d_out;

    bf16* ws = (bf16*)d_ws;
    const size_t M1 = (size_t)1024 * 1024;
    bf16* xb    = ws;                   // 4M
    bf16* WqkvT = ws + 4 * M1;          // 3M contiguous (WqT|WkT|WvT)
    bf16* WoT   = ws + 7 * M1;          // 1M
    bf16* Qw    = ws + 8 * M1;          // Q|K contiguous, 4M each
    bf16* Vtw   = ws + 16 * M1;         // 4M ([bh][d][s])
    bf16* Ow    = ws + 20 * M1;         // 4M

    prep<<<8192, 256, 0, stream>>>(x, Wq, Wk, Wv, Wo,
                                   xb, WqkvT, WqkvT + M1, WqkvT + 2 * M1, WoT);

    qkv_gemm<<<dim3(3072 / 128, BS_ / 128), 256, 0, stream>>>(xb, WqkvT, bq, bk, bv, Qw, Vtw);

    flash4<<<dim3(B_ * H_, 32), 256, 0, stream>>>(Qw, Qw + PER, Vtw, Ow);

    gemm128f<<<dim3(1024 / 128, BS_ / 128), 256, 0, stream>>>(Ow, WoT, bo, out);
}